// Round 3
// baseline (1901.242 us; speedup 1.0000x reference)
//
#include <hip/hip_runtime.h>

// Problem constants
#define H   512
#define W   512
#define C   256
#define KH  11
#define KW  11
#define OH  502
#define OW  502
#define OUT_MAP (OH * OW)   // 252004
#define HWSZ (H * W)

// Tiling: 64x64 tile (best halo/FETCH geometry), 16x16 threads, 4x4 px/thread.
#define TX 4
#define TY 4
#define TILE_X 64
#define TILE_Y 64
#define IN_Y  (TILE_Y + KH - 1)    // 74
#define IN_XP 76                   // padded LDS row stride (floats)
#define SLAB  (IN_Y * IN_XP)       // 5624 floats = 22496 B per buffer
#define VEC_PER_ROW 19             // 19 float4 = 76 floats per row
#define NSTAGE_TOT (IN_Y * VEC_PER_ROW)   // 1406
#define NSTAGE_IT  6                      // ceil(1406/256)
#define CPB   32                   // grid 8x8x8 = 512 blocks = 2/CU exact
#define WROW  12                   // padded weight row (floats, 16B-aligned)
#define WPC   (KH * WROW)          // 132 floats per channel

// Static component selectors — fold to registers under full unroll.
#define AVAL(A, j) ((j & 3) == 0 ? A[(j) >> 2].x : (j & 3) == 1 ? A[(j) >> 2].y : \
                    (j & 3) == 2 ? A[(j) >> 2].z : A[(j) >> 2].w)
#define WVAL(s, j) ((j & 3) == 0 ? wr[s][(j) >> 2].x : (j & 3) == 1 ? wr[s][(j) >> 2].y : \
                    (j & 3) == 2 ? wr[s][(j) >> 2].z : wr[s][(j) >> 2].w)

// One input row r of the sliding window. AVC holds row r (loaded last row);
// AVN receives row r+1 (issued FIRST so its ~120cyc LDS latency hides under
// this row's ~350cyc of FMAs). Weight row r+1 enters its rolling slot AFTER
// dy=3 consumed the slot's old contents (program order = WAR-safe).
#define ROW(r, AVC, AVN)                                                      \
  {                                                                           \
    if ((r) < TY + KH - 2) {                                                  \
      _Pragma("unroll")                                                       \
      for (int k = 0; k < 4; ++k)                                             \
        AVN[k] = *(const float4*)(rbase + ((r) + 1) * IN_XP + k * 4);         \
    }                                                                         \
    if ((r) - 3 >= 0 && (r) - 3 < KH) {  /* dy=3 first: uses oldest slot */   \
      _Pragma("unroll")                                                       \
      for (int kw = 0; kw < KW; ++kw) {                                       \
        const float wv = WVAL(((r) - 3) & 3, kw);                             \
        _Pragma("unroll")                                                     \
        for (int i = 0; i < TX; ++i) acc[3][i] += AVAL(AVC, kw + i) * wv;     \
      }                                                                       \
    }                                                                         \
    if ((r) + 1 < KH) {                  /* weight row r+1 -> rolling slot */ \
      wr[((r) + 1) & 3][0] = *(const float4*)(swc + ((r) + 1) * WROW + 0);    \
      wr[((r) + 1) & 3][1] = *(const float4*)(swc + ((r) + 1) * WROW + 4);    \
      wr[((r) + 1) & 3][2] = *(const float4*)(swc + ((r) + 1) * WROW + 8);    \
    }                                                                         \
    _Pragma("unroll")                                                         \
    for (int dy = 0; dy < 3; ++dy) {                                          \
      if ((r) - dy >= 0 && (r) - dy < KH) {                                   \
        _Pragma("unroll")                                                     \
        for (int kw = 0; kw < KW; ++kw) {                                     \
          const float wv = WVAL(((r) - dy) & 3, kw);                          \
          _Pragma("unroll")                                                   \
          for (int i = 0; i < TX; ++i) acc[dy][i] += AVAL(AVC, kw + i) * wv;  \
        }                                                                     \
      }                                                                       \
    }                                                                         \
  }

__global__ __launch_bounds__(256, 2)   // allow up to 256 VGPR; 2 blocks/CU
void conv_kernel(const float* __restrict__ x, const float* __restrict__ w,
                 float* __restrict__ out)
{
    __shared__ float s_in[2][SLAB];      // 2 x 22496 B (double buffer)
    __shared__ float s_w[CPB * WPC];     // 16896 B -> total 61888 B, 2 blocks/CU

    const int tid = threadIdx.x;
    const int tx  = tid & 15;
    const int ty  = tid >> 4;
    const int x0  = blockIdx.x * TILE_X;
    const int y0  = blockIdx.y * TILE_Y;
    const int c0  = blockIdx.z * CPB;

    // ---- weights -> LDS once per block, [ch][kh][12] 16B-aligned rows ----
    for (int it = tid; it < CPB * (KH * KW); it += 256) {
        const int ch  = it / 121;
        const int rem = it - ch * 121;
        const int kh  = rem / 11;
        const int kw  = rem - kh * 11;
        s_w[ch * WPC + kh * WROW + kw] = w[(size_t)(c0 + ch) * 121 + rem];
    }

    // ---- channel-invariant staging descriptors (clamped; garbage cells only
    // feed out-of-range outputs, which are discarded at the epilogue) ----
    int s_goff[NSTAGE_IT], s_loff[NSTAGE_IT];
#pragma unroll
    for (int j = 0; j < NSTAGE_IT; ++j) {
        int i = tid + j * 256;
        if (i >= NSTAGE_TOT) i = NSTAGE_TOT - 1;   // dup write, same value
        const int row = i / VEC_PER_ROW;
        const int vec = i - row * VEC_PER_ROW;
        const int gy  = min(y0 + row, H - 1);
        const int gx  = min(x0 + vec * 4, W - 4);
        s_goff[j] = gy * W + gx;
        s_loff[j] = row * IN_XP + vec * 4;
    }

    float acc[TY][TX];
#pragma unroll
    for (int dy = 0; dy < TY; ++dy)
#pragma unroll
        for (int i = 0; i < TX; ++i) acc[dy][i] = 0.f;

    const int ry0 = ty * TY;
    const int cx0 = tx * TX;

    // ---- prologue: prefetch ch c0, batch-sum into buf0, single barrier ----
    float4 pa[NSTAGE_IT], pb[NSTAGE_IT];
    {
        const float* __restrict__ p0 = x + (size_t)c0 * HWSZ;
        const float* __restrict__ p1 = p0 + (size_t)C * HWSZ;
#pragma unroll
        for (int j = 0; j < NSTAGE_IT; ++j) {
            pa[j] = *(const float4*)(p0 + s_goff[j]);
            pb[j] = *(const float4*)(p1 + s_goff[j]);
        }
        float* dbase = s_in[0];
#pragma unroll
        for (int j = 0; j < NSTAGE_IT; ++j)
            *(float4*)(dbase + s_loff[j]) =
                make_float4(pa[j].x + pb[j].x, pa[j].y + pb[j].y,
                            pa[j].z + pb[j].z, pa[j].w + pb[j].w);
    }
    __syncthreads();

    int cur = 0;
#pragma unroll 1
    for (int cc = 0; cc < CPB; ++cc) {
        // ---- issue next channel's global loads first: ~900cyc HBM latency
        // hides under this channel's ~5000cyc compute phase ----
        if (cc + 1 < CPB) {
            const float* __restrict__ p0 = x + (size_t)(c0 + cc + 1) * HWSZ;
            const float* __restrict__ p1 = p0 + (size_t)C * HWSZ;
#pragma unroll
            for (int j = 0; j < NSTAGE_IT; ++j) {
                pa[j] = *(const float4*)(p0 + s_goff[j]);
                pb[j] = *(const float4*)(p1 + s_goff[j]);
            }
        }

        // ---- compute from buf[cur]; all in-loop loads are DS (in-order
        // lgkm -> compiler can fine-count), everything issued a row ahead ----
        const float* rbase = s_in[cur] + ry0 * IN_XP + cx0;
        const float* swc   = s_w + cc * WPC;
        float4 wr[4][3];            // rolling 4-row weight window
        float4 av0[4], av1[4];      // double-buffered data row
#pragma unroll
        for (int k = 0; k < 4; ++k) av0[k] = *(const float4*)(rbase + k * 4);
        wr[0][0] = *(const float4*)(swc + 0);
        wr[0][1] = *(const float4*)(swc + 4);
        wr[0][2] = *(const float4*)(swc + 8);

        ROW(0,  av0, av1); ROW(1,  av1, av0); ROW(2,  av0, av1); ROW(3,  av1, av0);
        ROW(4,  av0, av1); ROW(5,  av1, av0); ROW(6,  av0, av1); ROW(7,  av1, av0);
        ROW(8,  av0, av1); ROW(9,  av1, av0); ROW(10, av0, av1); ROW(11, av1, av0);
        ROW(12, av0, av1); ROW(13, av1, av0);

        // ---- drain prefetch into the other buffer; vmcnt wait fully hidden
        // by the compute above; ONE barrier per channel ----
        if (cc + 1 < CPB) {
            float* dbase = s_in[cur ^ 1];
#pragma unroll
            for (int j = 0; j < NSTAGE_IT; ++j)
                *(float4*)(dbase + s_loff[j]) =
                    make_float4(pa[j].x + pb[j].x, pa[j].y + pb[j].y,
                                pa[j].z + pb[j].z, pa[j].w + pb[j].w);
            __syncthreads();
        }
        cur ^= 1;
    }

    // ---- accumulate partials into bias-initialized output (batch 0 map) ----
#pragma unroll
    for (int dy = 0; dy < TY; ++dy) {
        const int oy = y0 + ry0 + dy;
        if (oy < OH) {
#pragma unroll
            for (int i = 0; i < TX; ++i) {
                const int ox = x0 + cx0 + i;
                if (ox < OW)
                    atomicAdd(&out[(size_t)oy * OW + ox], acc[dy][i]);
            }
        }
    }
}

__global__ void init_kernel(float* __restrict__ out, const float* __restrict__ bias)
{
    const int i = blockIdx.x * 256 + threadIdx.x;
    if (i < OUT_MAP) out[i] = bias[0];
}

__global__ void bcast_kernel(float* __restrict__ out)
{
    const int i = blockIdx.x * 256 + threadIdx.x;
    if (i < OUT_MAP) out[OUT_MAP + i] = out[i];
}

extern "C" void kernel_launch(void* const* d_in, const int* in_sizes, int n_in,
                              void* d_out, int out_size, void* d_ws, size_t ws_size,
                              hipStream_t stream)
{
    const float* x    = (const float*)d_in[0];   // (2,256,512,512) fp32
    const float* w    = (const float*)d_in[1];   // (1,256,11,11)  fp32
    const float* bias = (const float*)d_in[2];   // (1,)           fp32
    float* out = (float*)d_out;                  // (2,1,502,502)  fp32

    const int nb = (OUT_MAP + 255) / 256;
    init_kernel<<<nb, 256, 0, stream>>>(out, bias);
    conv_kernel<<<dim3(8, 8, 8), 256, 0, stream>>>(x, w, out);
    bcast_kernel<<<nb, 256, 0, stream>>>(out);
}

// Round 4
// 897.881 us; speedup vs baseline: 2.1175x; 2.1175x over previous
//
#include <hip/hip_runtime.h>

// Problem constants
#define H   512
#define W   512
#define C   256
#define KH  11
#define KW  11
#define OH  502
#define OW  502
#define OUT_MAP (OH * OW)   // 252004
#define HWSZ (H * W)

// Tiling — identical to the 325us champion: 64x64 tile, 16x16 threads, 4x4/thread.
#define TX 4
#define TY 4
#define TILE_X 64
#define TILE_Y 64
#define IN_X  (TILE_X + KW - 1)   // 74
#define IN_Y  (TILE_Y + KH - 1)   // 74
#define IN_XP 76                  // padded LDS row stride (floats)
#define CPB   16                  // grid 8x8x16 = 1024 blocks = 4/CU exact
#define VEC_PER_ROW 19            // 19 float4 = 76 floats staged per row
#define NSTAGE_TOT (IN_Y * VEC_PER_ROW)   // 1406 float4 slots
#define NSTAGE_IT  6                      // ceil(1406/256)
#define WROW 12                   // padded weight row (floats, 16B-aligned)
#define WPC  (KH * WROW)          // 132 floats per channel in LDS

// Weight-row component selector (kw is compile-time under unroll -> folds).
#define WSEL(kw) ((kw) < 4 ? ((kw & 3) == 0 ? w0.x : (kw & 3) == 1 ? w0.y : \
                              (kw & 3) == 2 ? w0.z : w0.w)                  \
                : (kw) < 8 ? ((kw & 3) == 0 ? w1.x : (kw & 3) == 1 ? w1.y : \
                              (kw & 3) == 2 ? w1.z : w1.w)                  \
                :            ((kw & 3) == 0 ? w2.x : (kw & 3) == 1 ? w2.y : \
                              (kw & 3) == 2 ? w2.z : w2.w))

__global__ __launch_bounds__(256, 4)   // <=128 VGPR; LDS 30.9KB -> 4 blocks/CU
void conv_kernel(const float* __restrict__ x, const float* __restrict__ w,
                 float* __restrict__ out)
{
    __shared__ float s_in[IN_Y * IN_XP];   // 22496 B
    __shared__ float s_w[CPB * WPC];       // 8448 B  -> total 30944 B

    const int tid = threadIdx.x;
    const int tx  = tid & 15;
    const int ty  = tid >> 4;
    const int x0  = blockIdx.x * TILE_X;
    const int y0  = blockIdx.y * TILE_Y;
    const int c0  = blockIdx.z * CPB;

    // ---- weights -> LDS once per block, repacked [ch][kh][12] (16B rows).
    // ONLY change vs the 325us kernel: in-loop weight reads become broadcast
    // ds_read (in-order lgkm) instead of SMEM s_load (out-of-order lgkm whose
    // every use forces lgkmcnt(0), draining the ds_read pipeline).
    for (int it = tid; it < CPB * (KH * KW); it += 256) {
        const int ch  = it / 121;
        const int rem = it - ch * 121;
        const int kh  = rem / 11;
        const int kw  = rem - kh * 11;
        s_w[ch * WPC + kh * WROW + kw] = w[(size_t)(c0 + ch) * 121 + rem];
    }
    // first __syncthreads below (after data staging) makes s_w visible.

    // ---- channel-invariant staging descriptors (clamped; garbage cells only
    // feed out-of-range outputs, which are discarded at the epilogue) ----
    int s_goff[NSTAGE_IT];
    int s_loff[NSTAGE_IT];
    bool s_act[NSTAGE_IT];
#pragma unroll
    for (int j = 0; j < NSTAGE_IT; ++j) {
        int i = tid + j * 256;
        const bool act = (i < NSTAGE_TOT);
        if (!act) i = 0;
        const int row = i / VEC_PER_ROW;
        const int vec = i - row * VEC_PER_ROW;
        const int gy  = min(y0 + row, H - 1);
        const int gx  = min(x0 + vec * 4, W - 4);
        s_goff[j] = gy * W + gx;
        s_loff[j] = row * IN_XP + vec * 4;
        s_act[j]  = act;
    }

    float acc[TY][TX];
#pragma unroll
    for (int dy = 0; dy < TY; ++dy)
#pragma unroll
        for (int i = 0; i < TX; ++i) acc[dy][i] = 0.f;

    const int ry0 = ty * TY;
    const int cx0 = tx * TX;

    // ---- register prefetch of channel c0 (both batches) ----
    float4 pa[NSTAGE_IT], pb[NSTAGE_IT];
    {
        const float* __restrict__ p0 = x + (size_t)c0 * HWSZ;
        const float* __restrict__ p1 = p0 + (size_t)C * HWSZ;
#pragma unroll
        for (int j = 0; j < NSTAGE_IT; ++j) {
            pa[j] = *(const float4*)(p0 + s_goff[j]);
            pb[j] = *(const float4*)(p1 + s_goff[j]);
        }
    }

#pragma unroll 1
    for (int cc = 0; cc < CPB; ++cc) {
        // ---- drain prefetched regs: batch-sum and write tile to LDS ----
#pragma unroll
        for (int j = 0; j < NSTAGE_IT; ++j) {
            if (s_act[j]) {
                *(float4*)&s_in[s_loff[j]] =
                    make_float4(pa[j].x + pb[j].x, pa[j].y + pb[j].y,
                                pa[j].z + pb[j].z, pa[j].w + pb[j].w);
            }
        }
        __syncthreads();

        // ---- issue next channel's loads inside the compute window ----
        if (cc + 1 < CPB) {
            const float* __restrict__ p0 = x + (size_t)(c0 + cc + 1) * HWSZ;
            const float* __restrict__ p1 = p0 + (size_t)C * HWSZ;
#pragma unroll
            for (int j = 0; j < NSTAGE_IT; ++j) {
                pa[j] = *(const float4*)(p0 + s_goff[j]);
                pb[j] = *(const float4*)(p1 + s_goff[j]);
            }
        }

        // ---- compute: sliding-row window; weights via broadcast ds_read_b128
        // (12-float transient footprint; no SMEM in the loop body) ----
        const float* __restrict__ swc = s_w + cc * WPC;
#pragma unroll
        for (int r = 0; r < TY + KH - 1; ++r) {      // 14 rows
            const float* rp = &s_in[(ry0 + r) * IN_XP + cx0];
            const float4 a0 = *(const float4*)(rp + 0);
            const float4 a1 = *(const float4*)(rp + 4);
            const float4 a2 = *(const float4*)(rp + 8);
            const float4 a3 = *(const float4*)(rp + 12);
            const float win[16] = {a0.x, a0.y, a0.z, a0.w,
                                   a1.x, a1.y, a1.z, a1.w,
                                   a2.x, a2.y, a2.z, a2.w,
                                   a3.x, a3.y, a3.z, a3.w};
#pragma unroll
            for (int dy = 0; dy < TY; ++dy) {
                const int kh = r - dy;
                if (kh >= 0 && kh < KH) {
                    const float* wrow = swc + kh * WROW;
                    const float4 w0 = *(const float4*)(wrow + 0);
                    const float4 w1 = *(const float4*)(wrow + 4);
                    const float4 w2 = *(const float4*)(wrow + 8);
#pragma unroll
                    for (int kw = 0; kw < KW; ++kw) {
                        const float wv = WSEL(kw);
#pragma unroll
                        for (int i = 0; i < TX; ++i)
                            acc[dy][i] += win[kw + i] * wv;
                    }
                }
            }
        }
        __syncthreads();
    }

    // ---- accumulate partials into bias-initialized output (batch 0 map) ----
#pragma unroll
    for (int dy = 0; dy < TY; ++dy) {
        const int oy = y0 + ry0 + dy;
        if (oy < OH) {
#pragma unroll
            for (int i = 0; i < TX; ++i) {
                const int ox = x0 + cx0 + i;
                if (ox < OW)
                    atomicAdd(&out[(size_t)oy * OW + ox], acc[dy][i]);
            }
        }
    }
}

__global__ void init_kernel(float* __restrict__ out, const float* __restrict__ bias)
{
    const int i = blockIdx.x * 256 + threadIdx.x;
    if (i < OUT_MAP) out[i] = bias[0];
}

__global__ void bcast_kernel(float* __restrict__ out)
{
    const int i = blockIdx.x * 256 + threadIdx.x;
    if (i < OUT_MAP) out[OUT_MAP + i] = out[i];
}

extern "C" void kernel_launch(void* const* d_in, const int* in_sizes, int n_in,
                              void* d_out, int out_size, void* d_ws, size_t ws_size,
                              hipStream_t stream)
{
    const float* x    = (const float*)d_in[0];   // (2,256,512,512) fp32
    const float* w    = (const float*)d_in[1];   // (1,256,11,11)  fp32
    const float* bias = (const float*)d_in[2];   // (1,)           fp32
    float* out = (float*)d_out;                  // (2,1,502,502)  fp32

    const int nb = (OUT_MAP + 255) / 256;
    init_kernel<<<nb, 256, 0, stream>>>(out, bias);
    conv_kernel<<<dim3(8, 8, 16), 256, 0, stream>>>(x, w, out);
    bcast_kernel<<<nb, 256, 0, stream>>>(out);
}

// Round 5
// 866.253 us; speedup vs baseline: 2.1948x; 1.0365x over previous
//
#include <hip/hip_runtime.h>

// Problem constants
#define H   512
#define W   512
#define C   256
#define KH  11
#define KW  11
#define OH  502
#define OW  502
#define OUT_MAP (OH * OW)   // 252004
#define HWSZ (H * W)

// Tiling — champion geometry: 64x64 tile, 16x16 threads, 4x4 px/thread.
#define TX 4
#define TY 4
#define TILE_X 64
#define TILE_Y 64
#define IN_Y  74
#define UPR   19                  // 16B units per LDS row (76 floats incl 2 pad)
#define IN_XP 76                  // floats per row; 76 = 19*4 -> slot-linear LDS
#define NSTAGE_TOT (IN_Y * UPR)   // 1406 16B units per slab
#define NSTAGE_IT  6              // ceil(1406/256)
#define SLABF (NSTAGE_TOT * 4)    // floats per slab (22496 B)
#define CPB   16                  // grid 8x8x16 = 1024 blocks = 2 waves of 512 resident

// Direct global->LDS DMA, zero VGPR cost. LDS dest: HW uses wave-uniform base
// (readfirstlane) + lane*16; our slot mapping is exactly linear so per-lane or
// uniform base are equivalent. Global src is per-lane. Masked lanes skip.
__device__ __forceinline__ void gload16(const float* g, float* l)
{
    __builtin_amdgcn_global_load_lds(
        (const __attribute__((address_space(1))) void*)g,
        (__attribute__((address_space(3))) void*)l, 16, 0, 0);
}

__global__ __launch_bounds__(256, 2)
void conv_kernel(const float* __restrict__ x, const float* __restrict__ w,
                 float* __restrict__ out)
{
    // 3 rotating slabs: {batch0(c), batch1(c), free-for-prefetch}
    // 3 x 22496 B = 67488 B -> 2 blocks/CU (LDS-capped, by design).
    __shared__ float s_slab[3][SLABF];

    const int tid = threadIdx.x;
    const int tx  = tid & 15;
    const int ty  = tid >> 4;
    const int x0  = blockIdx.x * TILE_X;
    const int y0  = blockIdx.y * TILE_Y;
    const int c0  = blockIdx.z * CPB;

    // ---- channel-invariant staging descriptors (clamped; garbage cells only
    // feed out-of-range outputs, which are discarded at the epilogue) ----
    int  s_goff[NSTAGE_IT];
    bool s_act[NSTAGE_IT];
#pragma unroll
    for (int j = 0; j < NSTAGE_IT; ++j) {
        int i = tid + j * 256;
        const bool act = (i < NSTAGE_TOT);
        if (!act) i = 0;
        const int row = i / UPR;
        const int vec = i - row * UPR;
        const int gy  = min(y0 + row, H - 1);
        const int gx  = min(x0 + vec * 4, W - 4);
        s_goff[j] = gy * W + gx;
        s_act[j]  = act;
    }
    const int wub = (tid >> 6) * 64;   // wave-uniform slot base within a j-chunk

    float acc[TY][TX];
#pragma unroll
    for (int dy = 0; dy < TY; ++dy)
#pragma unroll
        for (int i = 0; i < TX; ++i) acc[dy][i] = 0.f;

    const int ry0 = ty * TY;
    const int cx0 = tx * TX;

    // ---- prologue: issue channel c0's loads (both batches) ----
    {
        const float* p0 = x + (size_t)c0 * HWSZ;
        const float* p1 = p0 + (size_t)C * HWSZ;
#pragma unroll
        for (int j = 0; j < NSTAGE_IT; ++j) {
            if (s_act[j]) {
                gload16(p0 + s_goff[j], &s_slab[0][(j * 256 + wub) * 4]);
                gload16(p1 + s_goff[j], &s_slab[1][(j * 256 + wub) * 4]);
            }
        }
    }

    float* sa = s_slab[0];   // batch0(c)  -> becomes summed tile
    float* sb = s_slab[1];   // batch1(c)  -> dead after sum; prefetch dest
    float* sf = s_slab[2];   // free       -> prefetch dest

#pragma unroll 1
    for (int cc = 0; cc < CPB; ++cc) {
        // barrier doubles as vmcnt(0) drain: deposits for channel cc complete
        // (they had the whole previous compute phase to fly).
        __syncthreads();

        // ---- batch-sum in LDS: sa += sb (conflict-free linear b128) ----
#pragma unroll
        for (int j = 0; j < NSTAGE_IT; ++j) {
            if (s_act[j]) {
                const int o = (tid + j * 256) * 4;
                const float4 a = *(const float4*)&sa[o];
                const float4 b = *(const float4*)&sb[o];
                *(float4*)&sa[o] =
                    make_float4(a.x + b.x, a.y + b.y, a.z + b.z, a.w + b.w);
            }
        }
        __syncthreads();

        // ---- issue channel cc+1's loads into (sb, sf): zero VGPR cost,
        // ~8000 cycles of compute ahead of their consumption ----
        if (cc + 1 < CPB) {
            const float* p0 = x + (size_t)(c0 + cc + 1) * HWSZ;
            const float* p1 = p0 + (size_t)C * HWSZ;
#pragma unroll
            for (int j = 0; j < NSTAGE_IT; ++j) {
                if (s_act[j]) {
                    gload16(p0 + s_goff[j], &sb[(j * 256 + wub) * 4]);
                    gload16(p1 + s_goff[j], &sf[(j * 256 + wub) * 4]);
                }
            }
        }

        // ---- compute from sa: champion inner loop, byte-identical math ----
        const float* __restrict__ wc = w + (size_t)(c0 + cc) * (KH * KW);
#pragma unroll
        for (int r = 0; r < TY + KH - 1; ++r) {      // 14 rows
            const float* rp = &sa[(ry0 + r) * IN_XP + cx0];
            const float4 a0 = *(const float4*)(rp + 0);
            const float4 a1 = *(const float4*)(rp + 4);
            const float4 a2 = *(const float4*)(rp + 8);
            const float4 a3 = *(const float4*)(rp + 12);
            const float win[16] = {a0.x, a0.y, a0.z, a0.w,
                                   a1.x, a1.y, a1.z, a1.w,
                                   a2.x, a2.y, a2.z, a2.w,
                                   a3.x, a3.y, a3.z, a3.w};
#pragma unroll
            for (int dy = 0; dy < TY; ++dy) {
                const int kh = r - dy;
                if (kh >= 0 && kh < KH) {
#pragma unroll
                    for (int kw = 0; kw < KW; ++kw) {
                        const float wv = wc[kh * KW + kw];   // uniform -> s_load
#pragma unroll
                        for (int i = 0; i < TX; ++i)
                            acc[dy][i] += win[kw + i] * wv;
                    }
                }
            }
        }

        // rotate slab roles: (a,b,f) <- (b,f,a)
        float* t = sa; sa = sb; sb = sf; sf = t;
    }

    // ---- accumulate partials into bias-initialized output (batch 0 map) ----
#pragma unroll
    for (int dy = 0; dy < TY; ++dy) {
        const int oy = y0 + ry0 + dy;
        if (oy < OH) {
#pragma unroll
            for (int i = 0; i < TX; ++i) {
                const int ox = x0 + cx0 + i;
                if (ox < OW)
                    atomicAdd(&out[(size_t)oy * OW + ox], acc[dy][i]);
            }
        }
    }
}

__global__ void init_kernel(float* __restrict__ out, const float* __restrict__ bias)
{
    const int i = blockIdx.x * 256 + threadIdx.x;
    if (i < OUT_MAP) out[i] = bias[0];
}

__global__ void bcast_kernel(float* __restrict__ out)
{
    const int i = blockIdx.x * 256 + threadIdx.x;
    if (i < OUT_MAP) out[OUT_MAP + i] = out[i];
}

extern "C" void kernel_launch(void* const* d_in, const int* in_sizes, int n_in,
                              void* d_out, int out_size, void* d_ws, size_t ws_size,
                              hipStream_t stream)
{
    const float* x    = (const float*)d_in[0];   // (2,256,512,512) fp32
    const float* w    = (const float*)d_in[1];   // (1,256,11,11)  fp32
    const float* bias = (const float*)d_in[2];   // (1,)           fp32
    float* out = (float*)d_out;                  // (2,1,502,502)  fp32

    const int nb = (OUT_MAP + 255) / 256;
    init_kernel<<<nb, 256, 0, stream>>>(out, bias);
    conv_kernel<<<dim3(8, 8, 16), 256, 0, stream>>>(x, w, out);
    bcast_kernel<<<nb, 256, 0, stream>>>(out);
}

// Round 6
// 838.425 us; speedup vs baseline: 2.2676x; 1.0332x over previous
//
#include <hip/hip_runtime.h>

// Problem constants
#define H   512
#define W   512
#define C   256
#define KH  11
#define KW  11
#define OH  502
#define OW  502
#define OUT_MAP (OH * OW)   // 252004
#define HWSZ (H * W)

// Tiling: 64x32 tile, 16x16 threads, 4x2 px/thread.
// Slab shrinks to 12.77KB so THREE slabs (async DMA pipeline) x 4 blocks/CU
// fit in 153KB LDS -> 16 waves/CU, 2x the TLP of round-5's 2-block config.
#define TX 4
#define TY 2
#define TILE_X 64
#define TILE_Y 32
#define IN_Y  (TILE_Y + KH - 1)   // 42
#define UPR   19                  // 16B units per LDS row (76 floats incl pad)
#define IN_XP 76                  // floats per row; slot-linear LDS
#define NSTAGE_TOT (IN_Y * UPR)   // 798 16B units per slab
#define NSTAGE_IT  4              // ceil(798/256)
#define SLABF (NSTAGE_TOT * 4)    // 3192 floats per slab (12768 B)
#define CPB   16                  // grid 8x16x16 = 2048 blocks = 2 rounds of 4/CU

// Direct global->LDS DMA, zero VGPR cost. LDS dest: wave-uniform base + lane*16
// (our slot mapping is exactly linear). Global src is per-lane; masked lanes skip.
__device__ __forceinline__ void gload16(const float* g, float* l)
{
    __builtin_amdgcn_global_load_lds(
        (const __attribute__((address_space(1))) void*)g,
        (__attribute__((address_space(3))) void*)l, 16, 0, 0);
}

__global__ __launch_bounds__(256, 4)
void conv_kernel(const float* __restrict__ x, const float* __restrict__ w,
                 float* __restrict__ out)
{
    // 3 rotating slabs: {summed(c), batch1-dead/prefetch, free-for-prefetch}
    // 3 x 12768 B = 38304 B -> 4 blocks/CU.
    __shared__ float s_slab[3][SLABF];

    const int tid = threadIdx.x;
    const int tx  = tid & 15;
    const int ty  = tid >> 4;
    const int x0  = blockIdx.x * TILE_X;
    const int y0  = blockIdx.y * TILE_Y;
    const int c0  = blockIdx.z * CPB;

    // ---- channel-invariant staging descriptors (clamped; garbage cells only
    // feed out-of-range outputs, which are discarded at the epilogue) ----
    int  s_goff[NSTAGE_IT];
    bool s_act[NSTAGE_IT];
#pragma unroll
    for (int j = 0; j < NSTAGE_IT; ++j) {
        int i = tid + j * 256;
        const bool act = (i < NSTAGE_TOT);
        if (!act) i = 0;
        const int row = i / UPR;
        const int vec = i - row * UPR;
        const int gy  = min(y0 + row, H - 1);
        const int gx  = min(x0 + vec * 4, W - 4);
        s_goff[j] = gy * W + gx;
        s_act[j]  = act;
    }
    const int wub = (tid >> 6) * 64;   // wave-uniform slot base within a j-chunk

    float acc[TY][TX];
#pragma unroll
    for (int dy = 0; dy < TY; ++dy)
#pragma unroll
        for (int i = 0; i < TX; ++i) acc[dy][i] = 0.f;

    const int ry0 = ty * TY;
    const int cx0 = tx * TX;

    // ---- prologue: issue channel c0's loads (both batches) ----
    {
        const float* p0 = x + (size_t)c0 * HWSZ;
        const float* p1 = p0 + (size_t)C * HWSZ;
#pragma unroll
        for (int j = 0; j < NSTAGE_IT; ++j) {
            if (s_act[j]) {
                gload16(p0 + s_goff[j], &s_slab[0][(j * 256 + wub) * 4]);
                gload16(p1 + s_goff[j], &s_slab[1][(j * 256 + wub) * 4]);
            }
        }
    }

    float* sa = s_slab[0];   // batch0(c)  -> becomes summed tile
    float* sb = s_slab[1];   // batch1(c)  -> dead after sum; prefetch dest
    float* sf = s_slab[2];   // free       -> prefetch dest

#pragma unroll 1
    for (int cc = 0; cc < CPB; ++cc) {
        // barrier doubles as vmcnt(0) drain: deposits for channel cc complete
        // (they had the whole previous compute phase to fly).
        __syncthreads();

        // ---- batch-sum in LDS: sa += sb (conflict-free linear b128) ----
#pragma unroll
        for (int j = 0; j < NSTAGE_IT; ++j) {
            if (s_act[j]) {
                const int o = (tid + j * 256) * 4;
                const float4 a = *(const float4*)&sa[o];
                const float4 b = *(const float4*)&sb[o];
                *(float4*)&sa[o] =
                    make_float4(a.x + b.x, a.y + b.y, a.z + b.z, a.w + b.w);
            }
        }
        __syncthreads();

        // ---- issue channel cc+1's loads into (sb, sf): zero VGPR cost,
        // a full compute phase ahead of their consumption ----
        if (cc + 1 < CPB) {
            const float* p0 = x + (size_t)(c0 + cc + 1) * HWSZ;
            const float* p1 = p0 + (size_t)C * HWSZ;
#pragma unroll
            for (int j = 0; j < NSTAGE_IT; ++j) {
                if (s_act[j]) {
                    gload16(p0 + s_goff[j], &sb[(j * 256 + wub) * 4]);
                    gload16(p1 + s_goff[j], &sf[(j * 256 + wub) * 4]);
                }
            }
        }

        // ---- compute from sa: sliding-row window, uniform weight s_loads ----
        const float* __restrict__ wc = w + (size_t)(c0 + cc) * (KH * KW);
#pragma unroll
        for (int r = 0; r < TY + KH - 1; ++r) {      // 12 rows
            const float* rp = &sa[(ry0 + r) * IN_XP + cx0];
            const float4 a0 = *(const float4*)(rp + 0);
            const float4 a1 = *(const float4*)(rp + 4);
            const float4 a2 = *(const float4*)(rp + 8);
            const float4 a3 = *(const float4*)(rp + 12);
            const float win[16] = {a0.x, a0.y, a0.z, a0.w,
                                   a1.x, a1.y, a1.z, a1.w,
                                   a2.x, a2.y, a2.z, a2.w,
                                   a3.x, a3.y, a3.z, a3.w};
#pragma unroll
            for (int dy = 0; dy < TY; ++dy) {
                const int kh = r - dy;
                if (kh >= 0 && kh < KH) {
#pragma unroll
                    for (int kw = 0; kw < KW; ++kw) {
                        const float wv = wc[kh * KW + kw];   // uniform -> s_load
#pragma unroll
                        for (int i = 0; i < TX; ++i)
                            acc[dy][i] += win[kw + i] * wv;
                    }
                }
            }
        }

        // rotate slab roles: (a,b,f) <- (b,f,a)
        float* t = sa; sa = sb; sb = sf; sf = t;
    }

    // ---- accumulate partials into bias-initialized output (batch 0 map) ----
#pragma unroll
    for (int dy = 0; dy < TY; ++dy) {
        const int oy = y0 + ry0 + dy;
        if (oy < OH) {
#pragma unroll
            for (int i = 0; i < TX; ++i) {
                const int ox = x0 + cx0 + i;
                if (ox < OW)
                    atomicAdd(&out[(size_t)oy * OW + ox], acc[dy][i]);
            }
        }
    }
}

__global__ void init_kernel(float* __restrict__ out, const float* __restrict__ bias)
{
    const int i = blockIdx.x * 256 + threadIdx.x;
    if (i < OUT_MAP) out[i] = bias[0];
}

__global__ void bcast_kernel(float* __restrict__ out)
{
    const int i = blockIdx.x * 256 + threadIdx.x;
    if (i < OUT_MAP) out[OUT_MAP + i] = out[i];
}

extern "C" void kernel_launch(void* const* d_in, const int* in_sizes, int n_in,
                              void* d_out, int out_size, void* d_ws, size_t ws_size,
                              hipStream_t stream)
{
    const float* x    = (const float*)d_in[0];   // (2,256,512,512) fp32
    const float* w    = (const float*)d_in[1];   // (1,256,11,11)  fp32
    const float* bias = (const float*)d_in[2];   // (1,)           fp32
    float* out = (float*)d_out;                  // (2,1,502,502)  fp32

    const int nb = (OUT_MAP + 255) / 256;
    init_kernel<<<nb, 256, 0, stream>>>(out, bias);
    conv_kernel<<<dim3(8, 16, 16), 256, 0, stream>>>(x, w, out);
    bcast_kernel<<<nb, 256, 0, stream>>>(out);
}